// Round 1
// baseline (531.373 us; speedup 1.0000x reference)
//
#include <hip/hip_runtime.h>
#include <hip/hip_bf16.h>
#include <stdint.h>

#define HH 128
#define WW 128
#define HWPX 16384
#define BIGL 16384           // background label / sentinel (fits uint16)
#define NT 1024
#define PPT 16               // pixels per thread
#define MAXC 4100            // >= max #components (4096) for 8-conn on 128x128

__device__ __forceinline__ unsigned um(unsigned a, unsigned b) { return a < b ? a : b; }

__global__ __launch_bounds__(NT)
void cc_kernel(const float* __restrict__ masks, float* __restrict__ losses) {
    __shared__ unsigned short L[HWPX];      // 32 KB: labels
    __shared__ int areaS[MAXC];             // 16.4 KB
    __shared__ unsigned short rootS[MAXC];  // 8.2 KB: compact id -> root flat index
    __shared__ int s_changed, s_ncomp, s_bg;
    __shared__ int s_r0, s_r1, s_c0, s_c1;
    __shared__ unsigned s_k2;
    __shared__ unsigned s_wk[32];           // per-wave top-2 pairs
    __shared__ float s_wsum[16];
    __shared__ float s_total;

    const int tid = threadIdx.x;
    const float* msk = masks + (size_t)blockIdx.x * HWPX;

    // ---- load, fg detect, total sum ----
    unsigned fgbits = 0;
    float tsum = 0.f;
#pragma unroll
    for (int k = 0; k < PPT; ++k) {
        int i = tid + k * NT;
        float v = msk[i];
        tsum += v;
        if (v > 0.f) { fgbits |= 1u << k; L[i] = (unsigned short)i; }
        else         { L[i] = (unsigned short)BIGL; }
    }
    for (int off = 32; off; off >>= 1) tsum += __shfl_down(tsum, off, 64);
    if ((tid & 63) == 0) s_wsum[tid >> 6] = tsum;
    if (tid == 0) { s_r0 = HH; s_r1 = -1; s_c0 = WW; s_c1 = -1; s_ncomp = 0; s_bg = 0; }
    __syncthreads();
    if (tid == 0) {
        float t = 0.f;
        for (int w = 0; w < 16; ++w) t += s_wsum[w];
        s_total = t;
    }

    // ---- CCL: min-label propagation + pointer jumping until stable ----
    for (int it = 0; it < 40000; ++it) {
        if (tid == 0) s_changed = 0;
        __syncthreads();
        bool any = false;
#pragma unroll
        for (int k = 0; k < PPT; ++k) {
            if (!(fgbits & (1u << k))) continue;
            int i = tid + k * NT;
            int r = i >> 7, c = i & 127;
            unsigned old = L[i];
            unsigned mv = old;
            if (r > 0) {
                int b = i - WW;
                if (c > 0)      mv = um(mv, L[b - 1]);
                mv = um(mv, L[b]);
                if (c < WW - 1) mv = um(mv, L[b + 1]);
            }
            if (c > 0)      mv = um(mv, L[i - 1]);
            if (c < WW - 1) mv = um(mv, L[i + 1]);
            if (r < HH - 1) {
                int b = i + WW;
                if (c > 0)      mv = um(mv, L[b - 1]);
                mv = um(mv, L[b]);
                if (c < WW - 1) mv = um(mv, L[b + 1]);
            }
            if (mv < BIGL) {                 // two pointer jumps (path compression)
                unsigned t2 = L[mv]; mv = um(mv, t2);
                t2 = L[mv];          mv = um(mv, t2);
            }
            if (mv < old) { L[i] = (unsigned short)mv; any = true; }
        }
        if (any) s_changed = 1;
        __syncthreads();
        int ch = s_changed;
        __syncthreads();                     // protect flag vs next-iter reset
        if (!ch) break;
    }

    // ---- save roots in registers ----
    unsigned short rr[PPT];
#pragma unroll
    for (int k = 0; k < PPT; ++k) rr[k] = L[tid + k * NT];
    __syncthreads();

    // ---- assign compact ids at roots (encode into L with 0x8000 flag) ----
#pragma unroll
    for (int k = 0; k < PPT; ++k) {
        int i = tid + k * NT;
        if ((fgbits & (1u << k)) && rr[k] == (unsigned short)i) {
            int c = atomicAdd(&s_ncomp, 1);
            rootS[c] = (unsigned short)i;
            L[i] = (unsigned short)(0x8000u | (unsigned)c);
        }
    }
    __syncthreads();
    int ncomp = s_ncomp;
    for (int c = tid; c < ncomp; c += NT) areaS[c] = 0;
    __syncthreads();

    // ---- areas ----
    int bgc = 0;
#pragma unroll
    for (int k = 0; k < PPT; ++k) {
        if (fgbits & (1u << k)) {
            int c = (int)(L[rr[k]] & 0x7FFFu);
            atomicAdd(&areaS[c], 1);
        } else {
            ++bgc;
        }
    }
    if (bgc) atomicAdd(&s_bg, bgc);
    __syncthreads();

    // ---- top-2 by key = (area<<15) | (BIGL - rootlabel)  [area desc, label asc] ----
    int bg = s_bg;
    int ncand = ncomp + (bg > 0 ? 1 : 0);
    unsigned b1 = 0, b2 = 0;
    for (int c = tid; c < ncand; c += NT) {
        unsigned a, ri;
        if (c < ncomp) { a = (unsigned)areaS[c]; ri = rootS[c]; }
        else           { a = (unsigned)bg;       ri = BIGL; }
        unsigned key = (a << 15) | (unsigned)(BIGL - (int)ri);
        if (key > b1) { b2 = b1; b1 = key; }
        else if (key > b2) b2 = key;
    }
    for (int off = 32; off; off >>= 1) {
        unsigned o1 = __shfl_down(b1, off, 64);
        unsigned o2 = __shfl_down(b2, off, 64);
        if (o1 > b1) { b2 = (b1 > o2 ? b1 : o2); b1 = o1; }
        else if (o1 > b2) b2 = o1;
    }
    if ((tid & 63) == 0) { s_wk[(tid >> 6) * 2] = b1; s_wk[(tid >> 6) * 2 + 1] = b2; }
    __syncthreads();
    if (tid == 0) {
        unsigned g1 = 0, g2 = 0;
        for (int w = 0; w < 16; ++w) {
            unsigned o1 = s_wk[w * 2], o2 = s_wk[w * 2 + 1];
            if (o1 > g1) { g2 = (g1 > o2 ? g1 : o2); g1 = o1; }
            else if (o1 > g2) g2 = o1;
        }
        s_k2 = g2;
    }
    __syncthreads();

    unsigned k2 = s_k2;
    bool have2 = (k2 >> 15) != 0;            // second-largest area > 0 (block-uniform)
    int j = BIGL - (int)(k2 & 0x7FFFu);      // root label of runner-up (BIGL == background)

    // ---- bbox of component j ----
    if (have2) {
        int lr0 = HH, lr1 = -1, lc0 = WW, lc1 = -1;
#pragma unroll
        for (int k = 0; k < PPT; ++k) {
            int i = tid + k * NT;
            bool inc = (fgbits & (1u << k)) ? ((int)rr[k] == j) : (j == BIGL);
            if (inc) {
                int r = i >> 7, c = i & 127;
                lr0 = min(lr0, r); lr1 = max(lr1, r);
                lc0 = min(lc0, c); lc1 = max(lc1, c);
            }
        }
        if (lr1 >= 0) {
            atomicMin(&s_r0, lr0); atomicMax(&s_r1, lr1);
            atomicMin(&s_c0, lc0); atomicMax(&s_c1, lc1);
        }
    }
    __syncthreads();

    // ---- sum inside box ----
    float bsum = 0.f;
    if (have2) {
        int r0 = s_r0, r1 = s_r1, c0 = s_c0, c1 = s_c1;
#pragma unroll
        for (int k = 0; k < PPT; ++k) {
            int i = tid + k * NT;
            int r = i >> 7, c = i & 127;
            if (r >= r0 && r <= r1 && c >= c0 && c <= c1) bsum += msk[i];
        }
    }
    for (int off = 32; off; off >>= 1) bsum += __shfl_down(bsum, off, 64);
    __syncthreads();
    if ((tid & 63) == 0) s_wsum[tid >> 6] = bsum;
    __syncthreads();
    if (tid == 0) {
        float b = 0.f;
        for (int w = 0; w < 16; ++w) b += s_wsum[w];
        losses[blockIdx.x] = (s_total - b) * (1.0f / 16384.0f);
    }
}

__global__ void reduce_kernel(const float* __restrict__ losses, float* __restrict__ out, int n) {
    __shared__ float s[4];
    int t = threadIdx.x;                      // 256 threads
    float v = 0.f;
    for (int i = t; i < n; i += 256) v += losses[i];
    for (int off = 32; off; off >>= 1) v += __shfl_down(v, off, 64);
    if ((t & 63) == 0) s[t >> 6] = v;
    __syncthreads();
    if (t == 0) out[0] = (s[0] + s[1] + s[2] + s[3]) / (float)n;
}

extern "C" void kernel_launch(void* const* d_in, const int* in_sizes, int n_in,
                              void* d_out, int out_size, void* d_ws, size_t ws_size,
                              hipStream_t stream) {
    const float* masks = (const float*)d_in[0];
    float* out = (float*)d_out;
    float* losses = (float*)d_ws;            // nmask floats of scratch
    int nmask = in_sizes[0] / HWPX;          // 8*16 = 128
    cc_kernel<<<nmask, NT, 0, stream>>>(masks, losses);
    reduce_kernel<<<1, 256, 0, stream>>>(losses, out, nmask);
}

// Round 2
// 98.783 us; speedup vs baseline: 5.3792x; 5.3792x over previous
//
#include <hip/hip_runtime.h>
#include <hip/hip_bf16.h>
#include <stdint.h>

#define HH 128
#define WW 128
#define HWPX 16384
#define BIGL 16384           // background sentinel (bg entries never change)
#define NT 1024
#define PPT 16               // contiguous pixels per thread (one 16-col row chunk)

// read-only root chase (safe during concurrent atomicMin unions: values only decrease)
__device__ __forceinline__ int findRoot(const int* L, int x) {
    int p = L[x];
    while (p != x) { x = p; p = L[x]; }
    return x;
}

// lock-free union by min index: final root of a component == min flat index
__device__ __forceinline__ void uni(int* L, int a, int b) {
    a = findRoot(L, a);
    b = findRoot(L, b);
    while (a != b) {
        if (a > b) { int t = a; a = b; b = t; }   // a < b: attach b under a
        int old = atomicMin(&L[b], a);
        if (old == b) break;                      // successfully linked
        b = findRoot(L, old);                     // b had moved; retry from its old parent
    }
}

__global__ __launch_bounds__(NT)
void cc_kernel(const float* __restrict__ masks, float* __restrict__ losses) {
    __shared__ int L[HWPX];          // 64 KB: UF parent; after flatten, roots get area<<16
    __shared__ int s_bg;
    __shared__ int s_r0, s_r1, s_c0, s_c1;
    __shared__ unsigned s_k2;
    __shared__ unsigned s_wk[32];    // per-wave top-2 pairs
    __shared__ float s_wsum[16];
    __shared__ float s_total;

    const int tid = threadIdx.x;
    const float* msk = masks + (size_t)blockIdx.x * HWPX;
    const int base = tid * PPT;      // 16-aligned -> whole chunk in one row
    const int row  = base >> 7;
    const int col0 = base & 127;

    // ---- vectorized load (4x float4), fg detect, total sum, UF init ----
    float vals[PPT];
    const float4* m4 = (const float4*)(msk + base);
#pragma unroll
    for (int q = 0; q < 4; ++q) {
        float4 v = m4[q];
        vals[q * 4 + 0] = v.x; vals[q * 4 + 1] = v.y;
        vals[q * 4 + 2] = v.z; vals[q * 4 + 3] = v.w;
    }
    unsigned fgbits = 0;
    float tsum = 0.f;
#pragma unroll
    for (int k = 0; k < PPT; ++k) {
        tsum += vals[k];
        int i = base + k;
        if (vals[k] > 0.f) { fgbits |= 1u << k; L[i] = i; }
        else               { L[i] = BIGL; }
    }
    for (int off = 32; off; off >>= 1) tsum += __shfl_down(tsum, off, 64);
    if ((tid & 63) == 0) s_wsum[tid >> 6] = tsum;
    if (tid == 0) { s_bg = 0; s_r0 = HH; s_r1 = -1; s_c0 = WW; s_c1 = -1; }
    __syncthreads();
    if (tid == 0) {
        float t = 0.f;
        for (int w = 0; w < 16; ++w) t += s_wsum[w];
        s_total = t;
    }

    // ---- single merge pass: union each fg pixel with its 4 forward 8-neighbors ----
    for (int k = 0; k < PPT; ++k) {
        if (!(fgbits & (1u << k))) continue;
        int i = base + k;
        int c = col0 + k;
        if (c < WW - 1 && L[i + 1] < BIGL) uni(L, i, i + 1);
        if (row < HH - 1) {
            int b = i + WW;
            if (c > 0      && L[b - 1] < BIGL) uni(L, i, b - 1);
            if (               L[b]     < BIGL) uni(L, i, b);
            if (c < WW - 1 && L[b + 1] < BIGL) uni(L, i, b + 1);
        }
    }
    __syncthreads();

    // ---- flatten: every fg pixel resolves its final root (no writes needed) ----
    int rr[PPT];
#pragma unroll
    for (int k = 0; k < PPT; ++k) {
        rr[k] = -1;
        if (fgbits & (1u << k)) rr[k] = findRoot(L, base + k);
    }
    __syncthreads();   // all finds complete before area bits corrupt parent chains

    // ---- areas into high 16 bits of root entries (run-length combined) ----
    {
        int prev = -1, cnt = 0, bgc = 0;
#pragma unroll
        for (int k = 0; k < PPT; ++k) {
            if (!(fgbits & (1u << k))) { ++bgc; continue; }
            int r = rr[k];
            if (r == prev) ++cnt;
            else {
                if (cnt) atomicAdd(&L[prev], cnt << 16);
                prev = r; cnt = 1;
            }
        }
        if (cnt) atomicAdd(&L[prev], cnt << 16);
        if (bgc) atomicAdd(&s_bg, bgc);
    }
    __syncthreads();

    // ---- top-2 by key = (area<<15) | (BIGL - label)  [area desc, label asc] ----
    int bg = s_bg;
    unsigned b1 = 0, b2 = 0;
    if (tid == 0 && bg > 0) b1 = ((unsigned)bg << 15);   // bg candidate, label BIGL -> suffix 0
    for (int i = tid; i < HWPX; i += NT) {
        int e = L[i];
        if ((e & 0xFFFF) == i && (e >> 16) != 0) {       // fg root (L[x]==x iff root)
            unsigned key = ((unsigned)(e >> 16) << 15) | (unsigned)(BIGL - i);
            if (key > b1) { b2 = b1; b1 = key; }
            else if (key > b2) b2 = key;
        }
    }
    for (int off = 32; off; off >>= 1) {
        unsigned o1 = __shfl_down(b1, off, 64);
        unsigned o2 = __shfl_down(b2, off, 64);
        if (o1 > b1) { b2 = (b1 > o2 ? b1 : o2); b1 = o1; }
        else if (o1 > b2) b2 = o1;
    }
    if ((tid & 63) == 0) { s_wk[(tid >> 6) * 2] = b1; s_wk[(tid >> 6) * 2 + 1] = b2; }
    __syncthreads();
    if (tid == 0) {
        unsigned g1 = 0, g2 = 0;
        for (int w = 0; w < 16; ++w) {
            unsigned o1 = s_wk[w * 2], o2 = s_wk[w * 2 + 1];
            if (o1 > g1) { g2 = (g1 > o2 ? g1 : o2); g1 = o1; }
            else if (o1 > g2) g2 = o1;
        }
        s_k2 = g2;
    }
    __syncthreads();

    unsigned k2 = s_k2;
    bool have2 = (k2 >> 15) != 0;            // second-largest area > 0
    int j = BIGL - (int)(k2 & 0x7FFFu);      // its label (BIGL == background)

    // ---- bbox of component j ----
    if (have2) {
        int lr0 = HH, lr1 = -1, lc0 = WW, lc1 = -1;
#pragma unroll
        for (int k = 0; k < PPT; ++k) {
            bool inc = (fgbits & (1u << k)) ? (rr[k] == j) : (j == BIGL);
            if (inc) {
                int c = col0 + k;
                lr0 = row; lr1 = row;        // whole chunk is one row
                lc0 = min(lc0, c); lc1 = max(lc1, c);
            }
        }
        if (lc1 >= 0) {
            atomicMin(&s_r0, lr0); atomicMax(&s_r1, lr1);
            atomicMin(&s_c0, lc0); atomicMax(&s_c1, lc1);
        }
    }
    __syncthreads();

    // ---- sum inside box (from registers) ----
    float bsum = 0.f;
    if (have2) {
        int r0 = s_r0, r1 = s_r1, c0 = s_c0, c1 = s_c1;
        if (row >= r0 && row <= r1) {
#pragma unroll
            for (int k = 0; k < PPT; ++k) {
                int c = col0 + k;
                if (c >= c0 && c <= c1) bsum += vals[k];
            }
        }
    }
    for (int off = 32; off; off >>= 1) bsum += __shfl_down(bsum, off, 64);
    __syncthreads();
    if ((tid & 63) == 0) s_wsum[tid >> 6] = bsum;
    __syncthreads();
    if (tid == 0) {
        float b = 0.f;
        for (int w = 0; w < 16; ++w) b += s_wsum[w];
        losses[blockIdx.x] = (s_total - b) * (1.0f / 16384.0f);
    }
}

__global__ void reduce_kernel(const float* __restrict__ losses, float* __restrict__ out, int n) {
    __shared__ float s[4];
    int t = threadIdx.x;                      // 256 threads
    float v = 0.f;
    for (int i = t; i < n; i += 256) v += losses[i];
    for (int off = 32; off; off >>= 1) v += __shfl_down(v, off, 64);
    if ((t & 63) == 0) s[t >> 6] = v;
    __syncthreads();
    if (t == 0) out[0] = (s[0] + s[1] + s[2] + s[3]) / (float)n;
}

extern "C" void kernel_launch(void* const* d_in, const int* in_sizes, int n_in,
                              void* d_out, int out_size, void* d_ws, size_t ws_size,
                              hipStream_t stream) {
    const float* masks = (const float*)d_in[0];
    float* out = (float*)d_out;
    float* losses = (float*)d_ws;            // nmask floats of scratch
    int nmask = in_sizes[0] / HWPX;          // 8*16 = 128
    cc_kernel<<<nmask, NT, 0, stream>>>(masks, losses);
    reduce_kernel<<<1, 256, 0, stream>>>(losses, out, nmask);
}

// Round 3
// 89.319 us; speedup vs baseline: 5.9491x; 1.1059x over previous
//
#include <hip/hip_runtime.h>
#include <hip/hip_bf16.h>
#include <stdint.h>

#define HH 128
#define WW 128
#define HWPX 16384
#define BIGL 16384           // background sentinel
#define NT 1024
#define PPT 16               // contiguous pixels per thread (one 16-col row chunk)

// read-only root chase (values only decrease under atomicMin unions)
__device__ __forceinline__ int findRoot(const int* L, int x) {
    int p = L[x];
    while (p != x) { x = p; p = L[x]; }
    return x;
}

// lock-free union by min index (validated in previous round)
__device__ __forceinline__ void uni(int* L, int a, int b) {
    a = findRoot(L, a);
    b = findRoot(L, b);
    while (a != b) {
        if (a > b) { int t = a; a = b; b = t; }   // a < b: attach b under a
        int old = atomicMin(&L[b], a);
        if (old == b) break;
        b = findRoot(L, old);
    }
}

__global__ __launch_bounds__(NT)
void cc_kernel(const float* __restrict__ masks, float* __restrict__ losses) {
    __shared__ int L[HWPX];              // 64 KB: UF parent; roots later get area<<16
    __shared__ unsigned rowbits[HH][4];  // 2 KB: fg bitmap, 128 bits per row
    __shared__ int s_bg;
    __shared__ int s_r0, s_r1, s_c0, s_c1;
    __shared__ unsigned s_k2;
    __shared__ unsigned s_wk[32];
    __shared__ float s_wsum[16];
    __shared__ float s_total;

    const int tid = threadIdx.x;
    const float* msk = masks + (size_t)blockIdx.x * HWPX;
    const int base = tid * PPT;          // 16-aligned: whole chunk in one row
    const int row  = base >> 7;
    const int col0 = base & 127;

    // ---- vectorized load, fg detect, total sum, run-head label init ----
    float vals[PPT];
    const float4* m4 = (const float4*)(msk + base);
#pragma unroll
    for (int q = 0; q < 4; ++q) {
        float4 v = m4[q];
        vals[q * 4 + 0] = v.x; vals[q * 4 + 1] = v.y;
        vals[q * 4 + 2] = v.z; vals[q * 4 + 3] = v.w;
    }
    unsigned fgbits = 0;
    float tsum = 0.f;
    {
        int start = -1;
#pragma unroll
        for (int k = 0; k < PPT; ++k) {
            tsum += vals[k];
            int i = base + k;
            if (vals[k] > 0.f) {
                fgbits |= 1u << k;
                if (start < 0) start = k;
                L[i] = base + start;       // chunk-local horizontal run head
            } else {
                start = -1;
                L[i] = BIGL;
            }
        }
    }
    // neighbor-chunk edge bits via shuffles (same wave: 8 chunks per row)
    const int lane = tid & 63;
    unsigned lf = __shfl(fgbits, lane > 0 ? lane - 1 : lane, 64);
    unsigned rf = __shfl(fgbits, lane < 63 ? lane + 1 : lane, 64);
    const unsigned leftbit  = (col0 > 0)   ? ((lf >> 15) & 1u) : 0u;
    const unsigned rightbit = (col0 < 112) ? (rf & 1u)         : 0u;
    // fg bitmap: pair of chunks -> one 32-bit word (even lane writes)
    unsigned other = __shfl_xor(fgbits, 1, 64);
    if (!(tid & 1)) rowbits[row][(tid >> 1) & 3] = fgbits | (other << 16);

    for (int off = 32; off; off >>= 1) tsum += __shfl_down(tsum, off, 64);
    if ((tid & 63) == 0) s_wsum[tid >> 6] = tsum;
    if (tid == 0) { s_bg = 0; s_r0 = HH; s_r1 = -1; s_c0 = WW; s_c1 = -1; }
    __syncthreads();
    if (tid == 0) {
        float t = 0.f;
        for (int w = 0; w < 16; ++w) t += s_wsum[w];
        s_total = t;
    }

    // ---- merge pass: dedup'd unions (new-upper-run rule) ----
    if (fgbits) {
        // upper-row window: bit j (0..17) = fg(row-1, col0-1+j)
        unsigned up = 0;
        if (row > 0) {
            const int wi  = col0 >> 5;
            const int off = col0 & 31;           // 0 or 16
            unsigned w0 = rowbits[row - 1][wi];
            unsigned w1 = (wi < 3) ? rowbits[row - 1][wi + 1] : 0u;
            unsigned long long uv = ((unsigned long long)w1 << 32) | w0;
            if (off == 16) {
                up = (unsigned)(uv >> 15) & 0x3FFFFu;
            } else {
                unsigned lw = (col0 > 0) ? rowbits[row - 1][wi - 1] : 0u;
                up = (unsigned)((uv << 1) | (lw >> 31)) & 0x3FFFFu;
            }
        }
        // horizontal stitch across chunk boundary
        if ((fgbits & 1u) && leftbit) uni(L, base, base - 1);

        unsigned m = fgbits;
        while (m) {
            int k = __ffs(m) - 1; m &= m - 1;
            int i = base + k;
            unsigned UL = (up >> k) & 1u;
            unsigned UP = (up >> (k + 1)) & 1u;
            unsigned UR = (up >> (k + 2)) & 1u;
            unsigned lF = k ? ((fgbits >> (k - 1)) & 1u) : leftbit;
            unsigned rF = (k < 15) ? ((fgbits >> (k + 1)) & 1u) : rightbit;
            if (!lF) {                           // run start
                if (UL)        uni(L, i, i - WW - 1);
                if (UP && !UL) uni(L, i, i - WW);
                if (UR && !UP) uni(L, i, i - WW + 1);
            } else {                             // continuation
                if (UP && !UL)        uni(L, i, i - WW);
                if (!rF && UR && !UP) uni(L, i, i - WW + 1);   // run end diagonal
            }
        }
    }
    __syncthreads();

    // ---- flatten: one find per chunk-local run; compress run heads ----
    int rr[PPT];
    {
        int cur = -1;
#pragma unroll
        for (int k = 0; k < PPT; ++k) {
            rr[k] = -1;
            if (fgbits & (1u << k)) {
                if (k == 0 || !(fgbits & (1u << (k - 1)))) {   // run head
                    cur = findRoot(L, base + k);
                    L[base + k] = cur;           // path compression (post-merge: safe)
                }
                rr[k] = cur;
            }
        }
    }
    __syncthreads();

    // ---- areas into high 16 bits of root entries (run-length combined) ----
    {
        int prev = -1, cnt = 0, bgc = 0;
#pragma unroll
        for (int k = 0; k < PPT; ++k) {
            if (!(fgbits & (1u << k))) { ++bgc; continue; }
            int r = rr[k];
            if (r == prev) ++cnt;
            else {
                if (cnt) atomicAdd(&L[prev], cnt << 16);
                prev = r; cnt = 1;
            }
        }
        if (cnt) atomicAdd(&L[prev], cnt << 16);
        if (bgc) atomicAdd(&s_bg, bgc);
    }
    __syncthreads();

    // ---- top-2 by key = (area<<15) | (BIGL - label)  [area desc, label asc] ----
    int bg = s_bg;
    unsigned b1 = 0, b2 = 0;
    if (tid == 0 && bg > 0) b1 = ((unsigned)bg << 15);   // bg candidate (label BIGL)
    for (int i = tid; i < HWPX; i += NT) {
        int e = L[i];
        if ((e & 0xFFFF) == i && (e >> 16) != 0) {       // fg root with area
            unsigned key = ((unsigned)(e >> 16) << 15) | (unsigned)(BIGL - i);
            if (key > b1) { b2 = b1; b1 = key; }
            else if (key > b2) b2 = key;
        }
    }
    for (int off = 32; off; off >>= 1) {
        unsigned o1 = __shfl_down(b1, off, 64);
        unsigned o2 = __shfl_down(b2, off, 64);
        if (o1 > b1) { b2 = (b1 > o2 ? b1 : o2); b1 = o1; }
        else if (o1 > b2) b2 = o1;
    }
    if ((tid & 63) == 0) { s_wk[(tid >> 6) * 2] = b1; s_wk[(tid >> 6) * 2 + 1] = b2; }
    __syncthreads();
    if (tid == 0) {
        unsigned g1 = 0, g2 = 0;
        for (int w = 0; w < 16; ++w) {
            unsigned o1 = s_wk[w * 2], o2 = s_wk[w * 2 + 1];
            if (o1 > g1) { g2 = (g1 > o2 ? g1 : o2); g1 = o1; }
            else if (o1 > g2) g2 = o1;
        }
        s_k2 = g2;
    }
    __syncthreads();

    unsigned k2 = s_k2;
    bool have2 = (k2 >> 15) != 0;
    int j = BIGL - (int)(k2 & 0x7FFFu);      // runner-up label (BIGL == background)

    // ---- bbox of component j ----
    if (have2) {
        int lc0 = WW, lc1 = -1;
#pragma unroll
        for (int k = 0; k < PPT; ++k) {
            bool inc = (fgbits & (1u << k)) ? (rr[k] == j) : (j == BIGL);
            if (inc) {
                int c = col0 + k;
                lc0 = min(lc0, c); lc1 = max(lc1, c);
            }
        }
        if (lc1 >= 0) {
            atomicMin(&s_r0, row); atomicMax(&s_r1, row);
            atomicMin(&s_c0, lc0); atomicMax(&s_c1, lc1);
        }
    }
    __syncthreads();

    // ---- sum inside box (from registers) ----
    float bsum = 0.f;
    if (have2) {
        int r0 = s_r0, r1 = s_r1, c0 = s_c0, c1 = s_c1;
        if (row >= r0 && row <= r1) {
#pragma unroll
            for (int k = 0; k < PPT; ++k) {
                int c = col0 + k;
                if (c >= c0 && c <= c1) bsum += vals[k];
            }
        }
    }
    for (int off = 32; off; off >>= 1) bsum += __shfl_down(bsum, off, 64);
    __syncthreads();
    if ((tid & 63) == 0) s_wsum[tid >> 6] = bsum;
    __syncthreads();
    if (tid == 0) {
        float b = 0.f;
        for (int w = 0; w < 16; ++w) b += s_wsum[w];
        losses[blockIdx.x] = (s_total - b) * (1.0f / 16384.0f);
    }
}

__global__ void reduce_kernel(const float* __restrict__ losses, float* __restrict__ out, int n) {
    __shared__ float s[4];
    int t = threadIdx.x;                      // 256 threads
    float v = 0.f;
    for (int i = t; i < n; i += 256) v += losses[i];
    for (int off = 32; off; off >>= 1) v += __shfl_down(v, off, 64);
    if ((t & 63) == 0) s[t >> 6] = v;
    __syncthreads();
    if (t == 0) out[0] = (s[0] + s[1] + s[2] + s[3]) / (float)n;
}

extern "C" void kernel_launch(void* const* d_in, const int* in_sizes, int n_in,
                              void* d_out, int out_size, void* d_ws, size_t ws_size,
                              hipStream_t stream) {
    const float* masks = (const float*)d_in[0];
    float* out = (float*)d_out;
    float* losses = (float*)d_ws;
    int nmask = in_sizes[0] / HWPX;          // 8*16 = 128
    cc_kernel<<<nmask, NT, 0, stream>>>(masks, losses);
    reduce_kernel<<<1, 256, 0, stream>>>(losses, out, nmask);
}

// Round 4
// 55.459 us; speedup vs baseline: 9.5813x; 1.6105x over previous
//
#include <hip/hip_runtime.h>
#include <hip/hip_bf16.h>
#include <stdint.h>

#define HH 128
#define WW 128
#define HWPX 16384
#define BIGL 16384           // background sentinel
#define NT 1024
#define PPT 16               // contiguous pixels per thread (one 16-col row chunk)

// find with path-halving via atomicMin (monotone, safe under concurrent unions)
__device__ __forceinline__ int findRootH(int* L, int x) {
    int p = L[x];
    while (p != x) {
        int g = L[p];
        if (g != p) atomicMin(&L[x], g);   // halving: g is a valid ancestor, g < p
        x = p; p = g;
    }
    return x;
}
// post-merge find with plain-store halving (no concurrent unions)
__device__ __forceinline__ int findRootF(int* L, int x) {
    int p = L[x];
    while (p != x) {
        int g = L[p];
        if (g != p) L[x] = g;
        x = p; p = g;
    }
    return p;
}
// lock-free union by min index
__device__ __forceinline__ void uni(int* L, int a, int b) {
    a = findRootH(L, a);
    b = findRootH(L, b);
    while (a != b) {
        if (a > b) { int t = a; a = b; b = t; }
        int old = atomicMin(&L[b], a);
        if (old == b) break;
        b = findRootH(L, old);
    }
}

__device__ __forceinline__ int wsumi(int v)   { for (int o = 32; o; o >>= 1) v += __shfl_xor(v, o, 64); return v; }
__device__ __forceinline__ float wsumf(float v){ for (int o = 32; o; o >>= 1) v += __shfl_xor(v, o, 64); return v; }
__device__ __forceinline__ int wmini(int v)   { for (int o = 32; o; o >>= 1) v = min(v, __shfl_xor(v, o, 64)); return v; }
__device__ __forceinline__ int wmaxi(int v)   { for (int o = 32; o; o >>= 1) v = max(v, __shfl_xor(v, o, 64)); return v; }

__global__ __launch_bounds__(NT)
void cc_kernel(const float* __restrict__ masks, float* __restrict__ losses) {
    __shared__ int L[HWPX];              // 64 KB: UF parent; roots later get area<<16
    __shared__ unsigned rowbits[HH][4];  // 2 KB: fg bitmap
    __shared__ int s_bg;
    __shared__ int s_r0, s_r1, s_c0, s_c1;
    __shared__ unsigned s_k2;
    __shared__ unsigned s_wk[32];
    __shared__ float s_wsum[16];
    __shared__ float s_total;

    const int tid = threadIdx.x;
    const int lane = tid & 63;
    const int wid = tid >> 6;
    const float* msk = masks + (size_t)blockIdx.x * HWPX;
    const int base = tid * PPT;
    const int row  = base >> 7;
    const int col0 = base & 127;

    // ---- vectorized load, fg detect, total sum, run-head label init ----
    float vals[PPT];
    const float4* m4 = (const float4*)(msk + base);
#pragma unroll
    for (int q = 0; q < 4; ++q) {
        float4 v = m4[q];
        vals[q * 4 + 0] = v.x; vals[q * 4 + 1] = v.y;
        vals[q * 4 + 2] = v.z; vals[q * 4 + 3] = v.w;
    }
    unsigned fgbits = 0;
    float tsum = 0.f;
    {
        int start = -1;
#pragma unroll
        for (int k = 0; k < PPT; ++k) {
            tsum += vals[k];
            int i = base + k;
            if (vals[k] > 0.f) {
                fgbits |= 1u << k;
                if (start < 0) start = k;
                L[i] = base + start;
            } else {
                start = -1;
                L[i] = BIGL;
            }
        }
    }
    unsigned lf = __shfl(fgbits, lane > 0 ? lane - 1 : lane, 64);
    unsigned rf = __shfl(fgbits, lane < 63 ? lane + 1 : lane, 64);
    const unsigned leftbit  = (col0 > 0)   ? ((lf >> 15) & 1u) : 0u;
    const unsigned rightbit = (col0 < 112) ? (rf & 1u)         : 0u;
    unsigned other = __shfl_xor(fgbits, 1, 64);
    if (!(tid & 1)) rowbits[row][(tid >> 1) & 3] = fgbits | (other << 16);

    tsum = wsumf(tsum);
    if (lane == 0) s_wsum[wid] = tsum;
    if (tid == 0) { s_bg = 0; s_r0 = HH; s_r1 = -1; s_c0 = WW; s_c1 = -1; }
    __syncthreads();

    // ---- wave0: total; all: merge pass (dedup'd unions) ----
    if (tid < 64) {
        float t = (tid < 16) ? s_wsum[tid] : 0.f;
        for (int o = 8; o; o >>= 1) t += __shfl_xor(t, o, 64);
        if (tid == 0) s_total = t;
    }
    if (fgbits) {
        unsigned up = 0;
        if (row > 0) {
            const int wi  = col0 >> 5;
            const int off = col0 & 31;
            unsigned w0 = rowbits[row - 1][wi];
            unsigned w1 = (wi < 3) ? rowbits[row - 1][wi + 1] : 0u;
            unsigned long long uv = ((unsigned long long)w1 << 32) | w0;
            if (off == 16) {
                up = (unsigned)(uv >> 15) & 0x3FFFFu;
            } else {
                unsigned lw = (col0 > 0) ? rowbits[row - 1][wi - 1] : 0u;
                up = (unsigned)((uv << 1) | (lw >> 31)) & 0x3FFFFu;
            }
        }
        if ((fgbits & 1u) && leftbit) uni(L, base, base - 1);
        unsigned m = fgbits;
        while (m) {
            int k = __ffs(m) - 1; m &= m - 1;
            int i = base + k;
            unsigned UL = (up >> k) & 1u;
            unsigned UP = (up >> (k + 1)) & 1u;
            unsigned UR = (up >> (k + 2)) & 1u;
            unsigned lF = k ? ((fgbits >> (k - 1)) & 1u) : leftbit;
            unsigned rF = (k < 15) ? ((fgbits >> (k + 1)) & 1u) : rightbit;
            if (!lF) {
                if (UL)        uni(L, i, i - WW - 1);
                if (UP && !UL) uni(L, i, i - WW);
                if (UR && !UP) uni(L, i, i - WW + 1);
            } else {
                if (UP && !UL)        uni(L, i, i - WW);
                if (!rF && UR && !UP) uni(L, i, i - WW + 1);
            }
        }
    }
    __syncthreads();

    // ---- flatten: one find per run; compress run heads; elect dominant root ----
    int rr[PPT];
    int firstRoot = 0x7FFFFFFF;
    {
        int cur = -1;
#pragma unroll
        for (int k = 0; k < PPT; ++k) {
            rr[k] = -1;
            if (fgbits & (1u << k)) {
                if (k == 0 || !(fgbits & (1u << (k - 1)))) {
                    cur = findRootF(L, base + k);
                    L[base + k] = cur;
                }
                rr[k] = cur;
                if (firstRoot == 0x7FFFFFFF) firstRoot = cur;
            }
        }
    }
    __syncthreads();

    // ---- areas: wave-combined for dominant root, run-length for the rest ----
    {
        const int R0 = wmini(firstRoot);          // wave-uniform hot root
        int giant = 0, bgc = 0, prev = -1, cnt = 0;
#pragma unroll
        for (int k = 0; k < PPT; ++k) {
            if (!(fgbits & (1u << k))) { ++bgc; continue; }
            int r = rr[k];
            if (r == R0) { ++giant; }
            else if (r == prev) ++cnt;
            else {
                if (cnt) atomicAdd(&L[prev], cnt << 16);
                prev = r; cnt = 1;
            }
        }
        if (cnt) atomicAdd(&L[prev], cnt << 16);
        int g = wsumi(giant);
        if (lane == 0 && R0 != 0x7FFFFFFF && g) atomicAdd(&L[R0], g << 16);
        int b = wsumi(bgc);
        if (lane == 0 && b) atomicAdd(&s_bg, b);
    }
    __syncthreads();

    // ---- top-2 by key = (area<<15) | (BIGL - label) ----
    int bg = s_bg;
    unsigned b1 = 0, b2 = 0;
    if (tid == 0 && bg > 0) b1 = ((unsigned)bg << 15);
    for (int i = tid; i < HWPX; i += NT) {
        int e = L[i];
        if ((e & 0xFFFF) == i && (e >> 16) != 0) {
            unsigned key = ((unsigned)(e >> 16) << 15) | (unsigned)(BIGL - i);
            if (key > b1) { b2 = b1; b1 = key; }
            else if (key > b2) b2 = key;
        }
    }
    for (int o = 32; o; o >>= 1) {
        unsigned p1 = __shfl_xor(b1, o, 64);
        unsigned p2 = __shfl_xor(b2, o, 64);
        if (p1 > b1) { b2 = (b1 > p2 ? b1 : p2); b1 = p1; }
        else if (p1 > b2) b2 = p1;
    }
    if (lane == 0) { s_wk[wid * 2] = b1; s_wk[wid * 2 + 1] = b2; }
    __syncthreads();
    if (tid < 64) {
        unsigned o1 = (tid < 16) ? s_wk[tid * 2] : 0u;
        unsigned o2 = (tid < 16) ? s_wk[tid * 2 + 1] : 0u;
        for (int o = 8; o; o >>= 1) {
            unsigned p1 = __shfl_xor(o1, o, 64);
            unsigned p2 = __shfl_xor(o2, o, 64);
            if (p1 > o1) { o2 = (o1 > p2 ? o1 : p2); o1 = p1; }
            else if (p1 > o2) o2 = p1;
        }
        if (tid == 0) s_k2 = o2;
    }
    __syncthreads();

    unsigned k2 = s_k2;
    bool have2 = (k2 >> 15) != 0;
    int j = BIGL - (int)(k2 & 0x7FFFu);      // runner-up label (BIGL == background)

    // ---- bbox of component j (wave-combined atomics) ----
    if (have2) {
        int lc0 = WW, lc1 = -1;
#pragma unroll
        for (int k = 0; k < PPT; ++k) {
            bool inc = (fgbits & (1u << k)) ? (rr[k] == j) : (j == BIGL);
            if (inc) {
                int c = col0 + k;
                lc0 = min(lc0, c); lc1 = max(lc1, c);
            }
        }
        int lr0 = (lc1 >= 0) ? row : HH;
        int lr1 = (lc1 >= 0) ? row : -1;
        lr0 = wmini(lr0); lr1 = wmaxi(lr1);
        lc0 = wmini(lc0); lc1 = wmaxi(lc1);
        if (lane == 0 && lr1 >= 0) {
            atomicMin(&s_r0, lr0); atomicMax(&s_r1, lr1);
            atomicMin(&s_c0, lc0); atomicMax(&s_c1, lc1);
        }
    }
    __syncthreads();

    // ---- sum inside box (from registers) ----
    float bsum = 0.f;
    if (have2) {
        int r0 = s_r0, r1 = s_r1, c0 = s_c0, c1 = s_c1;
        if (row >= r0 && row <= r1) {
#pragma unroll
            for (int k = 0; k < PPT; ++k) {
                int c = col0 + k;
                if (c >= c0 && c <= c1) bsum += vals[k];
            }
        }
    }
    bsum = wsumf(bsum);
    __syncthreads();
    if (lane == 0) s_wsum[wid] = bsum;
    __syncthreads();
    if (tid < 64) {
        float t = (tid < 16) ? s_wsum[tid] : 0.f;
        for (int o = 8; o; o >>= 1) t += __shfl_xor(t, o, 64);
        if (tid == 0) losses[blockIdx.x] = (s_total - t) * (1.0f / 16384.0f);
    }
}

__global__ void reduce_kernel(const float* __restrict__ losses, float* __restrict__ out, int n) {
    __shared__ float s[4];
    int t = threadIdx.x;                      // 256 threads
    float v = 0.f;
    for (int i = t; i < n; i += 256) v += losses[i];
    for (int off = 32; off; off >>= 1) v += __shfl_down(v, off, 64);
    if ((t & 63) == 0) s[t >> 6] = v;
    __syncthreads();
    if (t == 0) out[0] = (s[0] + s[1] + s[2] + s[3]) / (float)n;
}

extern "C" void kernel_launch(void* const* d_in, const int* in_sizes, int n_in,
                              void* d_out, int out_size, void* d_ws, size_t ws_size,
                              hipStream_t stream) {
    const float* masks = (const float*)d_in[0];
    float* out = (float*)d_out;
    float* losses = (float*)d_ws;
    int nmask = in_sizes[0] / HWPX;          // 8*16 = 128
    cc_kernel<<<nmask, NT, 0, stream>>>(masks, losses);
    reduce_kernel<<<1, 256, 0, stream>>>(losses, out, nmask);
}